// Round 16
// baseline (597.312 us; speedup 1.0000x reference)
//
#include <hip/hip_runtime.h>
#include <cstdint>
#include <cstddef>

#define D_TOK 1024
#define NH 16
#define DH 64
#define BATCH 8
#define SEQ 4096
#define M_TOT (BATCH * SEQ)   // 32768

typedef unsigned short u16;
typedef __attribute__((ext_vector_type(8))) __bf16 bf16x8;
typedef __attribute__((ext_vector_type(4))) float f32x4;

constexpr float INV_SQRT_DH = 0.125f;  // 1/sqrt(64)

__device__ __forceinline__ u16 f32_to_bf16_rne(float f) {
  union { float f; uint32_t u; } c; c.f = f;
  uint32_t r = (c.u + 0x7FFFu + ((c.u >> 16) & 1u)) >> 16;
  return (u16)r;
}
__device__ __forceinline__ float bf2f(u16 u) {
  union { uint32_t i; float f; } c;
  c.i = (uint32_t)u << 16;
  return c.f;
}

#define BAR() __builtin_amdgcn_s_barrier()
#define SCHB() __builtin_amdgcn_sched_barrier(0)
#define LGKM(N)                                                  \
  do {                                                           \
    asm volatile("s_waitcnt lgkmcnt(" #N ")" ::: "memory");      \
    SCHB();                                                      \
  } while (0)
#define VMW(N)                                                   \
  do {                                                           \
    asm volatile("s_waitcnt vmcnt(" #N ")" ::: "memory");        \
    SCHB();                                                      \
  } while (0)

#define GLD(GP, LP)                                               \
  __builtin_amdgcn_global_load_lds(                               \
      (const __attribute__((address_space(1))) void*)(GP),        \
      (__attribute__((address_space(3))) void*)(LP), 16, 0, 0)

// ---------------------------------------------------------------------------
// 128x128-tile bf16 GEMM, m97 structure: 256 thr (4 waves 2x2), ring-of-2
// LDS, syncthreads-only dbuf (compiler-scheduled lgkm; no asm waits),
// stage-before-compute (T3 minimum 2-phase). Multi-block/CU TLP covers the
// barrier drain. Cb0 = bf16(acc + bias0[n]).
// ---------------------------------------------------------------------------
template <int NN>   // N panels (N/128)
__global__ __launch_bounds__(256) void gemm128_bf16(
    const u16* __restrict__ A, const u16* __restrict__ W0,
    const float* __restrict__ bias0, u16* __restrict__ Cb0) {
  __shared__ u16 Sh[2][2][4096];  // slot x {A,B} x 8KB

  const int tid = threadIdx.x;
  const int lane = tid & 63;
  const int wid = tid >> 6;
  const int wr = wid >> 1;
  const int wc = wid & 1;
  const int lr = lane & 15;
  const int kg = lane >> 4;

  const int wg = blockIdx.x;
  const int cpx = gridDim.x >> 3;
  const int swz = (wg & 7) * cpx + (wg >> 3);
  const int bm0 = (swz / NN) * 128;
  const int bn0 = (swz % NN) * 128;

  f32x4 acc[4][4];
#pragma unroll
  for (int i = 0; i < 4; i++)
#pragma unroll
    for (int j = 0; j < 4; j++) acc[i][j] = (f32x4)0.f;

  const int srow = tid & 127;
  const int scg = tid >> 7;
  const u16* pA0 = A + (size_t)(bm0 + srow) * D_TOK + scg * 8;
  const u16* pB0 = W0 + (size_t)(bn0 + srow) * D_TOK + scg * 8;
  const int d0 = wid * 512;
  const int d1 = 2048 + wid * 512;
  const int aOff = (kg * 128 + wr * 64 + lr) * 16;
  const int bOff = (kg * 128 + wc * 64 + lr) * 16;

#define STG128(SL, REG)                                           \
  do {                                                            \
    const int _o = (REG) * 32;                                    \
    GLD(pA0 + _o, &Sh[SL][0][d0]);                                \
    GLD(pA0 + 16 + _o, &Sh[SL][0][d1]);                           \
    GLD(pB0 + _o, &Sh[SL][1][d0]);                                \
    GLD(pB0 + 16 + _o, &Sh[SL][1][d1]);                           \
  } while (0)

  STG128(0, 0);
  __syncthreads();  // buf0 globally ready (vmcnt+lgkm drained per wave + bar)

  for (int r = 0; r < 32; ++r) {
    const int sl = r & 1;
    if (r < 31) STG128(sl ^ 1, r + 1);  // prefetch next tile
    bf16x8 af[4], bv[4];
#pragma unroll
    for (int j = 0; j < 4; ++j)
      af[j] = *reinterpret_cast<const bf16x8*>(
          (const char*)&Sh[sl][0][0] + aOff + j * 256);
#pragma unroll
    for (int n = 0; n < 4; ++n)
      bv[n] = *reinterpret_cast<const bf16x8*>(
          (const char*)&Sh[sl][1][0] + bOff + n * 256);
#pragma unroll
    for (int j = 0; j < 4; ++j)
#pragma unroll
      for (int n = 0; n < 4; ++n)
        acc[j][n] = __builtin_amdgcn_mfma_f32_16x16x32_bf16(
            af[j], bv[n], acc[j][n], 0, 0, 0);
    __syncthreads();  // drains prefetch; next buf ready; WAR-safe
  }

#undef STG128

  float biasv[4];
#pragma unroll
  for (int ni = 0; ni < 4; ni++)
    biasv[ni] = bias0[bn0 + wc * 64 + ni * 16 + lr];
#pragma unroll
  for (int mi = 0; mi < 4; mi++) {
#pragma unroll
    for (int reg = 0; reg < 4; reg++) {
      const int m = bm0 + wr * 64 + mi * 16 + kg * 4 + reg;
#pragma unroll
      for (int ni = 0; ni < 4; ni++) {
        const int n = bn0 + wc * 64 + ni * 16 + lr;
        Cb0[(size_t)m * D_TOK + n] = f32_to_bf16_rne(acc[mi][ni][reg] + biasv[ni]);
      }
    }
  }
}

// ---------------------------------------------------------------------------
// bf16 MFMA GEMM, 256x256 tile (R7 schedule, proven 121 us / 655 TF).
// MODE 0: Cb0 = bf16(acc + bias0[n])
// MODE 2: C = acc + bias0[n] + bias1[b*1024+n] + bf2f(Rq); W = W0 + b*1M
// ---------------------------------------------------------------------------
template <int MODE, int NN>
__global__ __launch_bounds__(512, 2) void gemm_bf16(
    const u16* __restrict__ A, const u16* __restrict__ W0,
    const float* __restrict__ bias0, const float* __restrict__ bias1,
    float* __restrict__ C, u16* __restrict__ Cb0,
    const u16* __restrict__ Rq) {
  __shared__ u16 Sh[4][2][2][4096];

  const int tid = threadIdx.x;
  const int lane = tid & 63;
  const int wid = tid >> 6;
  const int wr = wid >> 2;
  const int wc = wid & 3;
  const int wch = wc >> 1;
  const int wcl = wc & 1;
  const int lr = lane & 15;
  const int kg = lane >> 4;

  const int wg = blockIdx.x;
  const int cpx = gridDim.x >> 3;
  const int swz = (wg & 7) * cpx + (wg >> 3);
  const int bm0 = (swz / NN) * 256;
  const int bn0 = (swz % NN) * 256;
  const int b = bm0 >> 12;

  const u16* Bp = (MODE == 2) ? W0 + (size_t)b * D_TOK * D_TOK : W0;

  f32x4 acc[8][4];
#pragma unroll
  for (int i = 0; i < 8; i++)
#pragma unroll
    for (int j = 0; j < 4; j++) acc[i][j] = (f32x4)0.f;

  const int srow = tid & 127;
  const int skc = tid >> 7;
  const u16* gpA0 = A + (size_t)(bm0 + srow) * D_TOK + skc * 8;
  const u16* gpA1 = gpA0 + (size_t)128 * D_TOK;
  const u16* gpB0 = Bp + (size_t)(bn0 + srow) * D_TOK + skc * 8;
  const u16* gpB1 = gpB0 + (size_t)128 * D_TOK;
  const int widOff = wid * 512;
  const int aOff = (kg * 128 + lr) * 16;
  const int bOff = (kg * 128 + wcl * 64 + lr) * 16;

#define STAGE4(SL, REG)                                           \
  do {                                                            \
    const int _o = (REG) * 32;                                    \
    GLD(gpA0 + _o, &Sh[SL][0][0][widOff]);                        \
    GLD(gpA1 + _o, &Sh[SL][0][1][widOff]);                        \
    GLD(gpB0 + _o, &Sh[SL][1][0][widOff]);                        \
    GLD(gpB1 + _o, &Sh[SL][1][1][widOff]);                        \
  } while (0)

#define RD_A0(SL, DST)                                            \
  _Pragma("unroll") for (int j = 0; j < 4; ++j)                   \
      DST[j] = *reinterpret_cast<const bf16x8*>(                  \
          (const char*)&Sh[SL][0][wr][0] + aOff + j * 256)

#define RD_A1(SL, DST)                                            \
  _Pragma("unroll") for (int j = 0; j < 4; ++j)                   \
      DST[j] = *reinterpret_cast<const bf16x8*>(                  \
          (const char*)&Sh[SL][0][wr][0] + 1024 + aOff + j * 256)

#define RD_B(SL, DST)                                             \
  _Pragma("unroll") for (int n = 0; n < 4; ++n)                   \
      DST[n] = *reinterpret_cast<const bf16x8*>(                  \
          (const char*)&Sh[SL][1][wch][0] + bOff + n * 256)

#define MFMA_LO(BV)                                               \
  do {                                                            \
    __builtin_amdgcn_s_setprio(1);                                \
    _Pragma("unroll") for (int j = 0; j < 4; ++j)                 \
        _Pragma("unroll") for (int n = 0; n < 4; ++n)             \
            acc[j][n] = __builtin_amdgcn_mfma_f32_16x16x32_bf16(  \
                af0[j], BV[n], acc[j][n], 0, 0, 0);               \
    __builtin_amdgcn_s_setprio(0);                                \
  } while (0)

#define MFMA_HI(BV)                                               \
  do {                                                            \
    __builtin_amdgcn_s_setprio(1);                                \
    _Pragma("unroll") for (int j = 0; j < 4; ++j)                 \
        _Pragma("unroll") for (int n = 0; n < 4; ++n)             \
            acc[4 + j][n] =                                       \
                __builtin_amdgcn_mfma_f32_16x16x32_bf16(          \
                    afm[j], BV[n], acc[4 + j][n], 0, 0, 0);       \
    __builtin_amdgcn_s_setprio(0);                                \
  } while (0)

  bf16x8 af0[4], afm[4], bvE[4], bvO[4];

  STAGE4(0, 0);
  STAGE4(1, 1);
  STAGE4(2, 2);
  VMW(8);
  BAR();
  RD_A0(0, af0);
  RD_B(0, bvE);

#define UREG(SL, BVC, BVN)                                        \
  do {                                                            \
    BAR();                                                        \
    STAGE4((SL + 3) & 3, rr + 3);                                 \
    RD_A1(SL, afm);                                               \
    LGKM(4);                                                      \
    MFMA_LO(BVC);                                                 \
    VMW(8);                                                       \
    RD_A0((SL + 1) & 3, af0);                                     \
    RD_B((SL + 1) & 3, BVN);                                      \
    LGKM(8);                                                      \
    MFMA_HI(BVC);                                                 \
    ++rr;                                                         \
  } while (0)

  int rr = 0;
  for (int o = 0; o < 7; ++o) {
    UREG(0, bvE, bvO);
    UREG(1, bvO, bvE);
    UREG(2, bvE, bvO);
    UREG(3, bvO, bvE);
  }
  BAR();
  STAGE4(3, 31);
  RD_A1(0, afm);
  LGKM(4); MFMA_LO(bvE);
  VMW(8);
  RD_A0(1, af0); RD_B(1, bvO);
  LGKM(8); MFMA_HI(bvE);
  BAR();
  RD_A1(1, afm);
  LGKM(4); MFMA_LO(bvO);
  VMW(4);
  RD_A0(2, af0); RD_B(2, bvE);
  LGKM(8); MFMA_HI(bvO);
  BAR();
  RD_A1(2, afm);
  LGKM(4); MFMA_LO(bvE);
  VMW(0);
  RD_A0(3, af0); RD_B(3, bvO);
  LGKM(8); MFMA_HI(bvE);
  BAR();
  RD_A1(3, afm);
  LGKM(4); MFMA_LO(bvO);
  LGKM(0); MFMA_HI(bvO);

#undef UREG
#undef MFMA_LO
#undef MFMA_HI
#undef RD_A0
#undef RD_A1
#undef RD_B
#undef STAGE4

  float biasv[4], b1v[4];
#pragma unroll
  for (int ni = 0; ni < 4; ni++) {
    const int n = bn0 + wc * 64 + ni * 16 + lr;
    biasv[ni] = bias0[n];
    if (MODE == 2) b1v[ni] = bias1[(size_t)b * D_TOK + n];
  }
#pragma unroll
  for (int mi = 0; mi < 8; mi++) {
#pragma unroll
    for (int reg = 0; reg < 4; reg++) {
      const int m = bm0 + wr * 128 + mi * 16 + kg * 4 + reg;
#pragma unroll
      for (int ni = 0; ni < 4; ni++) {
        const int n = bn0 + wc * 64 + ni * 16 + lr;
        float o = acc[mi][ni][reg] + biasv[ni];
        if (MODE == 0) {
          Cb0[(size_t)m * D_TOK + n] = f32_to_bf16_rne(o);
        } else {
          o += b1v[ni] + bf2f(Rq[(size_t)m * D_TOK + n]);
          C[(size_t)m * D_TOK + n] = o;
        }
      }
    }
  }
}

// ---------------------------------------------------------------------------
// logits via MFMA (2-phase syncthreads dbuf).
// alpha[t,h] = (X[t,:]·W[h,:] + bias[h] (+cbeta)) * 0.125
// ---------------------------------------------------------------------------
template <int BETA>
__global__ __launch_bounds__(256) void logits_mfma(
    const u16* __restrict__ X, const float* __restrict__ W,
    const float* __restrict__ bias, const float* __restrict__ cbeta,
    float* __restrict__ alpha) {
  __shared__ u16 Wl[NH][1032];
  __shared__ u16 Xs[2][4096];

  const int tid = threadIdx.x;
  const int lane = tid & 63;
  const int wid = tid >> 6;
  const int lr = lane & 15;
  const int kg = lane >> 4;

  const int t0 = blockIdx.x * 128;
  const int b = t0 >> 12;
  const float* Wsrc = BETA ? W + (size_t)b * NH * D_TOK : W;

  for (int i = tid; i < NH * D_TOK / 4; i += 256) {
    const int r = (i * 4) >> 10, c = (i * 4) & 1023;
    const float4 v = reinterpret_cast<const float4*>(Wsrc)[i];
    ushort4 o;
    o.x = f32_to_bf16_rne(v.x);
    o.y = f32_to_bf16_rne(v.y);
    o.z = f32_to_bf16_rne(v.z);
    o.w = f32_to_bf16_rne(v.w);
    *reinterpret_cast<ushort4*>(&Wl[r][c]) = o;
  }

  const int srow = tid & 127;
  const u16* pX = X + (size_t)(t0 + srow) * D_TOK + (tid >> 7) * 8;
  const int d0 = wid * 512;
  const int d1 = 2048 + wid * 512;
  const int aOff = (kg * 128 + wid * 32 + lr) * 16;

#define STGL(SL, REG)                                             \
  do {                                                            \
    const int _o = (REG) * 32;                                    \
    GLD(pX + _o, &Xs[SL][d0]);                                    \
    GLD(pX + 16 + _o, &Xs[SL][d1]);                               \
  } while (0)

  STGL(0, 0);
  __syncthreads();

  f32x4 acc[2];
  acc[0] = (f32x4)0.f;
  acc[1] = (f32x4)0.f;

  for (int r = 0; r < 32; ++r) {
    const int sl = r & 1;
    if (r < 31) STGL(sl ^ 1, r + 1);
    bf16x8 af[2], bv;
#pragma unroll
    for (int j = 0; j < 2; ++j)
      af[j] = *reinterpret_cast<const bf16x8*>(
          (const char*)&Xs[sl][0] + aOff + j * 256);
    bv = *reinterpret_cast<const bf16x8*>(
        (const char*)&Wl[lr][0] + r * 64 + kg * 16);
#pragma unroll
    for (int j = 0; j < 2; ++j)
      acc[j] = __builtin_amdgcn_mfma_f32_16x16x32_bf16(af[j], bv, acc[j], 0, 0, 0);
    __syncthreads();
  }

#undef STGL

  const float bv_ = bias[lr] + (BETA ? cbeta[b * NH + lr] : 0.f);
#pragma unroll
  for (int j = 0; j < 2; ++j) {
#pragma unroll
    for (int reg = 0; reg < 4; ++reg) {
      const int t = t0 + wid * 32 + j * 16 + kg * 4 + reg;
      alpha[(size_t)t * NH + lr] = (acc[j][reg] + bv_) * INV_SQRT_DH;
    }
  }
}

// ---------------------------------------------------------------------------
// fused: fp32->bf16 for x_q / x_kv / q_w (blocks 0..2047), v_w transpose
// (blocks 2048..2303), zero-fill of zmem (blocks 2304..2335).
// ---------------------------------------------------------------------------
__global__ __launch_bounds__(256) void cvt_all(
    const float* __restrict__ a, const float* __restrict__ bsrc,
    const float* __restrict__ qw, const float* __restrict__ v_w,
    u16* __restrict__ oa, u16* __restrict__ ob, u16* __restrict__ oqw,
    u16* __restrict__ vwT, float4* __restrict__ zmem, int zcount4) {
  __shared__ float tile[64][65];
  if (blockIdx.x < 2048) {
    const int half = M_TOT * D_TOK / 4;
    const int wq4 = D_TOK * D_TOK / 4;
    int i = blockIdx.x * 256 + threadIdx.x;
    const int stride = 2048 * 256;
    for (; i < 2 * half + wq4; i += stride) {
      const float* src;
      u16* dst;
      int j;
      if (i < half) { src = a; dst = oa; j = i; }
      else if (i < 2 * half) { src = bsrc; dst = ob; j = i - half; }
      else { src = qw; dst = oqw; j = i - 2 * half; }
      const float4 v = reinterpret_cast<const float4*>(src)[j];
      ushort4 o;
      o.x = f32_to_bf16_rne(v.x);
      o.y = f32_to_bf16_rne(v.y);
      o.z = f32_to_bf16_rne(v.z);
      o.w = f32_to_bf16_rne(v.w);
      reinterpret_cast<ushort4*>(dst)[j] = o;
    }
  } else if (blockIdx.x < 2304) {
    const int tb = blockIdx.x - 2048;
    const int r0 = (tb >> 4) * 64;
    const int c0 = (tb & 15) * 64;
    for (int i = threadIdx.x; i < 4096; i += 256) {
      const int r = i >> 6, c = i & 63;
      tile[r][c] = v_w[(size_t)(r0 + r) * D_TOK + c0 + c];
    }
    __syncthreads();
    for (int i = threadIdx.x; i < 4096; i += 256) {
      const int rr = i >> 6, cc = i & 63;
      vwT[(size_t)(c0 + rr) * D_TOK + r0 + cc] = f32_to_bf16_rne(tile[cc][rr]);
    }
  } else {
    const float4 z = make_float4(0.f, 0.f, 0.f, 0.f);
    for (int i = (blockIdx.x - 2304) * 256 + threadIdx.x; i < zcount4;
         i += 32 * 256)
      zmem[i] = z;
  }
}

// ---------------------------------------------------------------------------
// scale_vbt: owsc = bf16(out_w*kglb) AND vbt[b][n] += wave-reduced dot.
// ---------------------------------------------------------------------------
__global__ __launch_bounds__(256) void scale_vbt(
    const float* __restrict__ ow, const float* __restrict__ kglb,
    const float* __restrict__ v_b, u16* __restrict__ owsc,
    float* __restrict__ vbt) {
  const int per_b = D_TOK * D_TOK / 4;
  int i = blockIdx.x * 256 + threadIdx.x;
  const int stride = gridDim.x * 256;
  const int lane = threadIdx.x & 63;
  for (; i < BATCH * per_b; i += stride) {
    const int b = i >> 18, j = i & (per_b - 1);
    const int k4 = j & 255, n = j >> 8;
    const float4 w = reinterpret_cast<const float4*>(ow)[j];
    const float4 s = reinterpret_cast<const float4*>(kglb)[b * 256 + k4];
    const float4 v = reinterpret_cast<const float4*>(v_b)[k4];
    const float wsx = w.x * s.x, wsy = w.y * s.y, wsz = w.z * s.z,
                wsw = w.w * s.w;
    ushort4 o;
    o.x = f32_to_bf16_rne(wsx);
    o.y = f32_to_bf16_rne(wsy);
    o.z = f32_to_bf16_rne(wsz);
    o.w = f32_to_bf16_rne(wsw);
    reinterpret_cast<ushort4*>(owsc)[i] = o;
    float p = wsx * v.x + wsy * v.y + wsz * v.z + wsw * v.w;
#pragma unroll
    for (int off = 32; off; off >>= 1) p += __shfl_xor(p, off, 64);
    if (lane == 0) atomicAdd(&vbt[(size_t)b * D_TOK + n], p);
  }
}

// ---------------------------------------------------------------------------
// mb2: Mb[b][h][n] += sum_{d in chunk} k_w[d][n]*qg[b][d]*wk[h][d]
// ---------------------------------------------------------------------------
__global__ __launch_bounds__(256) void mb2_kernel(
    const float* __restrict__ k_w, const float* __restrict__ wk,
    const float* __restrict__ qg, const float* __restrict__ k_b,
    float* __restrict__ Mb, float* __restrict__ cbeta) {
  __shared__ float wq[128 * 16];
  const int bidx = blockIdx.x;
  const int b = bidx >> 5;
  const int nc = (bidx >> 3) & 3;
  const int dc = bidx & 7;
  const int n = nc * 256 + threadIdx.x;
  const int d0 = dc * 128;
  const int tid = threadIdx.x;

  for (int e = tid; e < 128 * 16; e += 256) {
    const int d = e >> 4, h = e & 15;
    wq[e] = qg[(size_t)b * D_TOK + d0 + d] * wk[(size_t)h * D_TOK + d0 + d];
  }
  __syncthreads();

  float acc[NH];
#pragma unroll
  for (int h = 0; h < NH; h++) acc[h] = 0.f;
#pragma unroll 4
  for (int d = 0; d < 128; ++d) {
    const float kv = k_w[(size_t)(d0 + d) * D_TOK + n];
#pragma unroll
    for (int h = 0; h < NH; h++) acc[h] += kv * wq[d * 16 + h];
  }
#pragma unroll
  for (int h = 0; h < NH; h++)
    atomicAdd(&Mb[((size_t)b * NH + h) * D_TOK + n], acc[h]);

  if (nc == 0 && tid < 64) {
    const int h = tid & 15, dl = tid >> 4;
    float c = 0.f;
    for (int d = dl; d < 128; d += 4)
      c += k_b[d0 + d] * wq[d * 16 + h];
    c += __shfl_xor(c, 16, 64);
    c += __shfl_xor(c, 32, 64);
    if (dl == 0) atomicAdd(&cbeta[b * NH + h], c);
  }
}

// ---------------------------------------------------------------------------
// kglb2: kglb[b][d] = qg[b][d]*(sum_n xp[b][h(d)][n]*k_w[d][n] + k_b[d])
// ---------------------------------------------------------------------------
__global__ __launch_bounds__(256) void kglb2_kernel(
    const float* __restrict__ xp, const float* __restrict__ k_w,
    const float* __restrict__ qg, const float* __restrict__ k_b,
    float* __restrict__ kglb) {
  __shared__ float xs[D_TOK];
  const int b = blockIdx.x >> 6;
  const int d0 = (blockIdx.x & 63) * 16;
  const int h = d0 >> 6;
  const int tid = threadIdx.x, lane = tid & 63, wv = tid >> 6;

  reinterpret_cast<float4*>(xs)[tid] =
      reinterpret_cast<const float4*>(xp + ((size_t)b * NH + h) * D_TOK)[tid];
  __syncthreads();

#pragma unroll
  for (int i = 0; i < 4; ++i) {
    const int d = d0 + wv * 4 + i;
    const float4* kr = reinterpret_cast<const float4*>(k_w + (size_t)d * D_TOK);
    float s = 0.f;
#pragma unroll
    for (int k4 = 0; k4 < 4; ++k4) {
      const int j4 = lane + k4 * 64;
      const float4 kv = kr[j4];
      const float4 xv = reinterpret_cast<const float4*>(xs)[j4];
      s += kv.x * xv.x + kv.y * xv.y + kv.z * xv.z + kv.w * xv.w;
    }
#pragma unroll
    for (int off = 32; off; off >>= 1) s += __shfl_xor(s, off, 64);
    if (lane == 0)
      kglb[(size_t)b * D_TOK + d] = qg[(size_t)b * D_TOK + d] * (s + k_b[d]);
  }
}

// ---------------------------------------------------------------------------
// Per-(b,h): max + 1/sum(exp) over tokens.
// ---------------------------------------------------------------------------
__global__ __launch_bounds__(256) void softmax_prep(
    const float* __restrict__ al, float* __restrict__ smx,
    float* __restrict__ sinv) {
  __shared__ float red[4];
  const int b = blockIdx.x >> 4, h = blockIdx.x & 15;
  const int tid = threadIdx.x, lane = tid & 63, wid = tid >> 6;
  const float* col = al + (size_t)b * SEQ * NH + h;

  float mx = -INFINITY;
  for (int t = tid; t < SEQ; t += 256) mx = fmaxf(mx, col[(size_t)t * NH]);
#pragma unroll
  for (int off = 32; off; off >>= 1) mx = fmaxf(mx, __shfl_xor(mx, off, 64));
  if (lane == 0) red[wid] = mx;
  __syncthreads();
  mx = fmaxf(fmaxf(red[0], red[1]), fmaxf(red[2], red[3]));
  __syncthreads();

  float s = 0.f;
  for (int t = tid; t < SEQ; t += 256) s += __expf(col[(size_t)t * NH] - mx);
#pragma unroll
  for (int off = 32; off; off >>= 1) s += __shfl_xor(s, off, 64);
  if (lane == 0) red[wid] = s;
  __syncthreads();
  if (tid == 0) {
    const float tot = red[0] + red[1] + red[2] + red[3];
    smx[blockIdx.x] = mx;
    sinv[blockIdx.x] = 1.0f / tot;
  }
}

// ---------------------------------------------------------------------------
// qg pool: qg[b,d] += sum_t softmaxw[t,h(d)] * q_bf[b,t,d]  (atomics)
// ---------------------------------------------------------------------------
__global__ __launch_bounds__(256) void pool_accum_bf(
    const float* __restrict__ al, const u16* __restrict__ src,
    const float* __restrict__ smx, const float* __restrict__ sinv,
    float* __restrict__ g) {
  constexpr int TCH = 64;
  const int b = blockIdx.x / (SEQ / TCH);
  const int t0 = (blockIdx.x % (SEQ / TCH)) * TCH;
  const int d0 = threadIdx.x * 4;
  const int h = d0 >> 6;
  const float mx = smx[b * NH + h];
  const float inv = sinv[b * NH + h];

  float4 acc = make_float4(0.f, 0.f, 0.f, 0.f);
  const float* ap = al + ((size_t)b * SEQ + t0) * NH + h;
  const u16* sp = src + ((size_t)b * SEQ + t0) * D_TOK + d0;
#pragma unroll 2
  for (int t = 0; t < TCH; t++) {
    const float wgt = __expf(ap[(size_t)t * NH] - mx) * inv;
    const ushort4 v = *reinterpret_cast<const ushort4*>(sp + (size_t)t * D_TOK);
    acc.x += wgt * bf2f(v.x);
    acc.y += wgt * bf2f(v.y);
    acc.z += wgt * bf2f(v.z);
    acc.w += wgt * bf2f(v.w);
  }
  float* gp = g + (size_t)b * D_TOK + d0;
  atomicAdd(gp + 0, acc.x);
  atomicAdd(gp + 1, acc.y);
  atomicAdd(gp + 2, acc.z);
  atomicAdd(gp + 3, acc.w);
}

// ---------------------------------------------------------------------------
// xp pool: xp[b][h][n] += sum_t beta[t,h]*x_kv[t,n].  Grid 256.
// ---------------------------------------------------------------------------
__global__ __launch_bounds__(256) void xp_pool(
    const float* __restrict__ al, const u16* __restrict__ x,
    const float* __restrict__ smx, const float* __restrict__ sinv,
    float* __restrict__ xp) {
  constexpr int TCH = 128;
  __shared__ float wl[TCH][NH];
  const int b = blockIdx.x >> 5;
  const int t0 = (blockIdx.x & 31) * TCH;
  const int tid = threadIdx.x;
  for (int i = tid; i < TCH * NH; i += 256) {
    const int tt = i >> 4, h = i & 15;
    wl[tt][h] = __expf(al[((size_t)(b * SEQ + t0 + tt)) * NH + h] -
                       smx[b * NH + h]) *
                sinv[b * NH + h];
  }
  __syncthreads();

  const int n0 = tid * 4;
  float acc[NH][4];
#pragma unroll
  for (int h = 0; h < NH; h++)
#pragma unroll
    for (int c = 0; c < 4; c++) acc[h][c] = 0.f;
  const u16* xpt = x + ((size_t)b * SEQ + t0) * D_TOK + n0;
  for (int tt = 0; tt < TCH; tt++) {
    const ushort4 v = *reinterpret_cast<const ushort4*>(xpt + (size_t)tt * D_TOK);
    const float x0 = bf2f(v.x), x1 = bf2f(v.y), x2 = bf2f(v.z), x3 = bf2f(v.w);
#pragma unroll
    for (int h = 0; h < NH; h++) {
      const float w = wl[tt][h];
      acc[h][0] += w * x0;
      acc[h][1] += w * x1;
      acc[h][2] += w * x2;
      acc[h][3] += w * x3;
    }
  }
#pragma unroll
  for (int h = 0; h < NH; h++)
#pragma unroll
    for (int c = 0; c < 4; c++)
      atomicAdd(&xp[((size_t)b * NH + h) * D_TOK + n0 + c], acc[h][c]);
}

// ---------------------------------------------------------------------------
extern "C" void kernel_launch(void* const* d_in, const int* in_sizes, int n_in,
                              void* d_out, int out_size, void* d_ws,
                              size_t ws_size, hipStream_t stream) {
  const float* x_q   = (const float*)d_in[0];
  const float* x_kv  = (const float*)d_in[1];
  const float* q_w   = (const float*)d_in[2];
  const float* k_w   = (const float*)d_in[3];
  const float* v_w   = (const float*)d_in[4];
  const float* wq_w  = (const float*)d_in[5];
  const float* wk_w  = (const float*)d_in[6];
  const float* out_w = (const float*)d_in[7];
  const float* q_b   = (const float*)d_in[8];
  const float* k_b   = (const float*)d_in[9];
  const float* v_b   = (const float*)d_in[10];
  const float* wq_b  = (const float*)d_in[11];
  const float* wk_b  = (const float*)d_in[12];
  const float* out_b = (const float*)d_in[13];
  float* out = (float*)d_out;

  char* ws = (char*)d_ws;
  const size_t SZ_BF  = (size_t)M_TOT * D_TOK * sizeof(u16);
  const size_t SZ_WBF = (size_t)D_TOK * D_TOK * sizeof(u16);
  size_t off = 0;
  u16* xq_bf  = (u16*)(ws + off); off += SZ_BF;
  u16* xkv_bf = (u16*)(ws + off); off += SZ_BF;
  u16* q_bf   = (u16*)(ws + off); off += SZ_BF;
  u16* qw_bf  = (u16*)(ws + off); off += SZ_WBF;
  u16* vwT_bf = (u16*)(ws + off); off += SZ_WBF;
  u16* owsc   = (u16*)(ws + off); off += BATCH * SZ_WBF;
  u16* Nbt    = (u16*)(ws + off); off += BATCH * SZ_WBF;
  float* al   = (float*)(ws + off); off += (size_t)M_TOT * NH * 4;
  float* kglb = (float*)(ws + off); off += BATCH * D_TOK * 4;
  float* smx0 = (float*)(ws + off); off += BATCH * NH * 4;
  float* sinv0= (float*)(ws + off); off += BATCH * NH * 4;
  float* smx1 = (float*)(ws + off); off += BATCH * NH * 4;
  float* sinv1= (float*)(ws + off); off += BATCH * NH * 4;
  // ---- contiguous zero-init region (zeroed inside cvt_all) ----
  char* zstart = ws + off;
  float* xp   = (float*)(ws + off); off += (size_t)BATCH * NH * D_TOK * 4;
  float* Mb   = (float*)(ws + off); off += (size_t)BATCH * NH * D_TOK * 4;
  float* qg   = (float*)(ws + off); off += BATCH * D_TOK * 4;
  float* vbt  = (float*)(ws + off); off += BATCH * D_TOK * 4;
  float* zb   = (float*)(ws + off); off += D_TOK * 4;
  float* cbeta= (float*)(ws + off); off += BATCH * NH * 4;
  const int ZC4 = (int)((ws + off - zstart) / 16);  // float4 count (16B mult)

  // fused conversions + v_w transpose + zero-init
  cvt_all<<<2336, 256, 0, stream>>>(x_q, x_kv, q_w, v_w, xq_bf, xkv_bf,
                                    qw_bf, vwT_bf, (float4*)zstart, ZC4);

  // q = bf16(x_q @ q_w^T + q_b)  — A/B: m97-structure gemm128 (syncthreads)
  gemm128_bf16<8><<<2048, 256, 0, stream>>>(xq_bf, qw_bf, q_b, q_bf);
  // alpha (MFMA) -> softmax -> q_global
  logits_mfma<0><<<256, 256, 0, stream>>>(q_bf, wq_w, wq_b, nullptr, al);
  softmax_prep<<<BATCH * NH, 256, 0, stream>>>(al, smx0, sinv0);
  pool_accum_bf<<<BATCH * (SEQ / 64), 256, 0, stream>>>(al, q_bf, smx0, sinv0,
                                                        qg);
  // Mb + cbeta
  mb2_kernel<<<256, 256, 0, stream>>>(k_w, wk_w, qg, k_b, Mb, cbeta);
  // beta logits (MFMA, per-batch Mb)
  logits_mfma<1><<<256, 256, 0, stream>>>(xkv_bf, Mb, wk_b, cbeta, al);
  softmax_prep<<<BATCH * NH, 256, 0, stream>>>(al, smx1, sinv1);
  // per-head pools of x_kv
  xp_pool<<<256, 256, 0, stream>>>(al, xkv_bf, smx1, sinv1, xp);
  // k_global
  kglb2_kernel<<<512, 256, 0, stream>>>(xp, k_w, qg, k_b, kglb);
  // owsc = out_w * kglb AND vbt, fused
  scale_vbt<<<1024, 256, 0, stream>>>(out_w, kglb, v_b, owsc, vbt);
  // compose on gemm128 (512 blocks)
  gemm128_bf16<8><<<512, 256, 0, stream>>>(owsc, vwT_bf, zb, Nbt);
  // out = x_kv @ Nbt_b^T + out_b + vbt_b + q  (control: proven 256^2 kernel)
  gemm_bf16<2, 4><<<512, 512, 0, stream>>>(xkv_bf, Nbt, out_b, vbt, out,
                                           nullptr, q_bf);
}

// Round 17
// 542.825 us; speedup vs baseline: 1.1004x; 1.1004x over previous
//
#include <hip/hip_runtime.h>
#include <cstdint>
#include <cstddef>

#define D_TOK 1024
#define NH 16
#define DH 64
#define BATCH 8
#define SEQ 4096
#define M_TOT (BATCH * SEQ)   // 32768

typedef unsigned short u16;
typedef __attribute__((ext_vector_type(8))) __bf16 bf16x8;
typedef __attribute__((ext_vector_type(4))) float f32x4;

constexpr float INV_SQRT_DH = 0.125f;  // 1/sqrt(64)

__device__ __forceinline__ u16 f32_to_bf16_rne(float f) {
  union { float f; uint32_t u; } c; c.f = f;
  uint32_t r = (c.u + 0x7FFFu + ((c.u >> 16) & 1u)) >> 16;
  return (u16)r;
}
__device__ __forceinline__ float bf2f(u16 u) {
  union { uint32_t i; float f; } c;
  c.i = (uint32_t)u << 16;
  return c.f;
}

#define BAR() __builtin_amdgcn_s_barrier()
#define SCHB() __builtin_amdgcn_sched_barrier(0)
#define LGKM(N)                                                  \
  do {                                                           \
    asm volatile("s_waitcnt lgkmcnt(" #N ")" ::: "memory");      \
    SCHB();                                                      \
  } while (0)
#define VMW(N)                                                   \
  do {                                                           \
    asm volatile("s_waitcnt vmcnt(" #N ")" ::: "memory");        \
    SCHB();                                                      \
  } while (0)

#define GLD(GP, LP)                                               \
  __builtin_amdgcn_global_load_lds(                               \
      (const __attribute__((address_space(1))) void*)(GP),        \
      (__attribute__((address_space(3))) void*)(LP), 16, 0, 0)

// ---------------------------------------------------------------------------
// 128x128-tile bf16 GEMM (2-phase syncthreads dbuf) — for the SMALL compose
// GEMM only (grid fill); measured inferior to gemm_bf16 on main GEMMs.
// Cb0 = bf16(acc + bias0[n]).
// ---------------------------------------------------------------------------
template <int NN>   // N panels (N/128)
__global__ __launch_bounds__(256) void gemm128_bf16(
    const u16* __restrict__ A, const u16* __restrict__ W0,
    const float* __restrict__ bias0, u16* __restrict__ Cb0) {
  __shared__ u16 Sh[2][2][4096];  // slot x {A,B} x 8KB

  const int tid = threadIdx.x;
  const int lane = tid & 63;
  const int wid = tid >> 6;
  const int wr = wid >> 1;
  const int wc = wid & 1;
  const int lr = lane & 15;
  const int kg = lane >> 4;

  const int wg = blockIdx.x;
  const int cpx = gridDim.x >> 3;
  const int swz = (wg & 7) * cpx + (wg >> 3);
  const int bm0 = (swz / NN) * 128;
  const int bn0 = (swz % NN) * 128;

  f32x4 acc[4][4];
#pragma unroll
  for (int i = 0; i < 4; i++)
#pragma unroll
    for (int j = 0; j < 4; j++) acc[i][j] = (f32x4)0.f;

  const int srow = tid & 127;
  const int scg = tid >> 7;
  const u16* pA0 = A + (size_t)(bm0 + srow) * D_TOK + scg * 8;
  const u16* pB0 = W0 + (size_t)(bn0 + srow) * D_TOK + scg * 8;
  const int d0 = wid * 512;
  const int d1 = 2048 + wid * 512;
  const int aOff = (kg * 128 + wr * 64 + lr) * 16;
  const int bOff = (kg * 128 + wc * 64 + lr) * 16;

#define STG128(SL, REG)                                           \
  do {                                                            \
    const int _o = (REG) * 32;                                    \
    GLD(pA0 + _o, &Sh[SL][0][d0]);                                \
    GLD(pA0 + 16 + _o, &Sh[SL][0][d1]);                           \
    GLD(pB0 + _o, &Sh[SL][1][d0]);                                \
    GLD(pB0 + 16 + _o, &Sh[SL][1][d1]);                           \
  } while (0)

  STG128(0, 0);
  __syncthreads();

  for (int r = 0; r < 32; ++r) {
    const int sl = r & 1;
    if (r < 31) STG128(sl ^ 1, r + 1);
    bf16x8 af[4], bv[4];
#pragma unroll
    for (int j = 0; j < 4; ++j)
      af[j] = *reinterpret_cast<const bf16x8*>(
          (const char*)&Sh[sl][0][0] + aOff + j * 256);
#pragma unroll
    for (int n = 0; n < 4; ++n)
      bv[n] = *reinterpret_cast<const bf16x8*>(
          (const char*)&Sh[sl][1][0] + bOff + n * 256);
#pragma unroll
    for (int j = 0; j < 4; ++j)
#pragma unroll
      for (int n = 0; n < 4; ++n)
        acc[j][n] = __builtin_amdgcn_mfma_f32_16x16x32_bf16(
            af[j], bv[n], acc[j][n], 0, 0, 0);
    __syncthreads();
  }

#undef STG128

  float biasv[4];
#pragma unroll
  for (int ni = 0; ni < 4; ni++)
    biasv[ni] = bias0[bn0 + wc * 64 + ni * 16 + lr];
#pragma unroll
  for (int mi = 0; mi < 4; mi++) {
#pragma unroll
    for (int reg = 0; reg < 4; reg++) {
      const int m = bm0 + wr * 64 + mi * 16 + kg * 4 + reg;
#pragma unroll
      for (int ni = 0; ni < 4; ni++) {
        const int n = bn0 + wc * 64 + ni * 16 + lr;
        Cb0[(size_t)m * D_TOK + n] = f32_to_bf16_rne(acc[mi][ni][reg] + biasv[ni]);
      }
    }
  }
}

// ---------------------------------------------------------------------------
// bf16 MFMA GEMM, 256x256 tile (R7 schedule, proven 120 us / 655 TF).
// MODE 0: Cb0 = bf16(acc + bias0[n])
// MODE 2: C = acc + bias0[n] + bias1[b*1024+n] + bf2f(Rq); W = W0 + b*1M
// ---------------------------------------------------------------------------
template <int MODE, int NN>
__global__ __launch_bounds__(512, 2) void gemm_bf16(
    const u16* __restrict__ A, const u16* __restrict__ W0,
    const float* __restrict__ bias0, const float* __restrict__ bias1,
    float* __restrict__ C, u16* __restrict__ Cb0,
    const u16* __restrict__ Rq) {
  __shared__ u16 Sh[4][2][2][4096];

  const int tid = threadIdx.x;
  const int lane = tid & 63;
  const int wid = tid >> 6;
  const int wr = wid >> 2;
  const int wc = wid & 3;
  const int wch = wc >> 1;
  const int wcl = wc & 1;
  const int lr = lane & 15;
  const int kg = lane >> 4;

  const int wg = blockIdx.x;
  const int cpx = gridDim.x >> 3;
  const int swz = (wg & 7) * cpx + (wg >> 3);
  const int bm0 = (swz / NN) * 256;
  const int bn0 = (swz % NN) * 256;
  const int b = bm0 >> 12;

  const u16* Bp = (MODE == 2) ? W0 + (size_t)b * D_TOK * D_TOK : W0;

  f32x4 acc[8][4];
#pragma unroll
  for (int i = 0; i < 8; i++)
#pragma unroll
    for (int j = 0; j < 4; j++) acc[i][j] = (f32x4)0.f;

  const int srow = tid & 127;
  const int skc = tid >> 7;
  const u16* gpA0 = A + (size_t)(bm0 + srow) * D_TOK + skc * 8;
  const u16* gpA1 = gpA0 + (size_t)128 * D_TOK;
  const u16* gpB0 = Bp + (size_t)(bn0 + srow) * D_TOK + skc * 8;
  const u16* gpB1 = gpB0 + (size_t)128 * D_TOK;
  const int widOff = wid * 512;
  const int aOff = (kg * 128 + lr) * 16;
  const int bOff = (kg * 128 + wcl * 64 + lr) * 16;

#define STAGE4(SL, REG)                                           \
  do {                                                            \
    const int _o = (REG) * 32;                                    \
    GLD(gpA0 + _o, &Sh[SL][0][0][widOff]);                        \
    GLD(gpA1 + _o, &Sh[SL][0][1][widOff]);                        \
    GLD(gpB0 + _o, &Sh[SL][1][0][widOff]);                        \
    GLD(gpB1 + _o, &Sh[SL][1][1][widOff]);                        \
  } while (0)

#define RD_A0(SL, DST)                                            \
  _Pragma("unroll") for (int j = 0; j < 4; ++j)                   \
      DST[j] = *reinterpret_cast<const bf16x8*>(                  \
          (const char*)&Sh[SL][0][wr][0] + aOff + j * 256)

#define RD_A1(SL, DST)                                            \
  _Pragma("unroll") for (int j = 0; j < 4; ++j)                   \
      DST[j] = *reinterpret_cast<const bf16x8*>(                  \
          (const char*)&Sh[SL][0][wr][0] + 1024 + aOff + j * 256)

#define RD_B(SL, DST)                                             \
  _Pragma("unroll") for (int n = 0; n < 4; ++n)                   \
      DST[n] = *reinterpret_cast<const bf16x8*>(                  \
          (const char*)&Sh[SL][1][wch][0] + bOff + n * 256)

#define MFMA_LO(BV)                                               \
  do {                                                            \
    __builtin_amdgcn_s_setprio(1);                                \
    _Pragma("unroll") for (int j = 0; j < 4; ++j)                 \
        _Pragma("unroll") for (int n = 0; n < 4; ++n)             \
            acc[j][n] = __builtin_amdgcn_mfma_f32_16x16x32_bf16(  \
                af0[j], BV[n], acc[j][n], 0, 0, 0);               \
    __builtin_amdgcn_s_setprio(0);                                \
  } while (0)

#define MFMA_HI(BV)                                               \
  do {                                                            \
    __builtin_amdgcn_s_setprio(1);                                \
    _Pragma("unroll") for (int j = 0; j < 4; ++j)                 \
        _Pragma("unroll") for (int n = 0; n < 4; ++n)             \
            acc[4 + j][n] =                                       \
                __builtin_amdgcn_mfma_f32_16x16x32_bf16(          \
                    afm[j], BV[n], acc[4 + j][n], 0, 0, 0);       \
    __builtin_amdgcn_s_setprio(0);                                \
  } while (0)

  bf16x8 af0[4], afm[4], bvE[4], bvO[4];

  STAGE4(0, 0);
  STAGE4(1, 1);
  STAGE4(2, 2);
  VMW(8);
  BAR();
  RD_A0(0, af0);
  RD_B(0, bvE);

#define UREG(SL, BVC, BVN)                                        \
  do {                                                            \
    BAR();                                                        \
    STAGE4((SL + 3) & 3, rr + 3);                                 \
    RD_A1(SL, afm);                                               \
    LGKM(4);                                                      \
    MFMA_LO(BVC);                                                 \
    VMW(8);                                                       \
    RD_A0((SL + 1) & 3, af0);                                     \
    RD_B((SL + 1) & 3, BVN);                                      \
    LGKM(8);                                                      \
    MFMA_HI(BVC);                                                 \
    ++rr;                                                         \
  } while (0)

  int rr = 0;
  for (int o = 0; o < 7; ++o) {
    UREG(0, bvE, bvO);
    UREG(1, bvO, bvE);
    UREG(2, bvE, bvO);
    UREG(3, bvO, bvE);
  }
  BAR();
  STAGE4(3, 31);
  RD_A1(0, afm);
  LGKM(4); MFMA_LO(bvE);
  VMW(8);
  RD_A0(1, af0); RD_B(1, bvO);
  LGKM(8); MFMA_HI(bvE);
  BAR();
  RD_A1(1, afm);
  LGKM(4); MFMA_LO(bvO);
  VMW(4);
  RD_A0(2, af0); RD_B(2, bvE);
  LGKM(8); MFMA_HI(bvO);
  BAR();
  RD_A1(2, afm);
  LGKM(4); MFMA_LO(bvE);
  VMW(0);
  RD_A0(3, af0); RD_B(3, bvO);
  LGKM(8); MFMA_HI(bvE);
  BAR();
  RD_A1(3, afm);
  LGKM(4); MFMA_LO(bvO);
  LGKM(0); MFMA_HI(bvO);

#undef UREG
#undef MFMA_LO
#undef MFMA_HI
#undef RD_A0
#undef RD_A1
#undef RD_B
#undef STAGE4

  float biasv[4], b1v[4];
#pragma unroll
  for (int ni = 0; ni < 4; ni++) {
    const int n = bn0 + wc * 64 + ni * 16 + lr;
    biasv[ni] = bias0[n];
    if (MODE == 2) b1v[ni] = bias1[(size_t)b * D_TOK + n];
  }
#pragma unroll
  for (int mi = 0; mi < 8; mi++) {
#pragma unroll
    for (int reg = 0; reg < 4; reg++) {
      const int m = bm0 + wr * 128 + mi * 16 + kg * 4 + reg;
#pragma unroll
      for (int ni = 0; ni < 4; ni++) {
        const int n = bn0 + wc * 64 + ni * 16 + lr;
        float o = acc[mi][ni][reg] + biasv[ni];
        if (MODE == 0) {
          Cb0[(size_t)m * D_TOK + n] = f32_to_bf16_rne(o);
        } else {
          o += b1v[ni] + bf2f(Rq[(size_t)m * D_TOK + n]);
          C[(size_t)m * D_TOK + n] = o;
        }
      }
    }
  }
}

// ---------------------------------------------------------------------------
// logits via MFMA (2-phase syncthreads dbuf).
// alpha[t,h] = (X[t,:]·W[h,:] + bias[h] (+cbeta)) * 0.125
// ---------------------------------------------------------------------------
template <int BETA>
__global__ __launch_bounds__(256) void logits_mfma(
    const u16* __restrict__ X, const float* __restrict__ W,
    const float* __restrict__ bias, const float* __restrict__ cbeta,
    float* __restrict__ alpha) {
  __shared__ u16 Wl[NH][1032];
  __shared__ u16 Xs[2][4096];

  const int tid = threadIdx.x;
  const int lane = tid & 63;
  const int wid = tid >> 6;
  const int lr = lane & 15;
  const int kg = lane >> 4;

  const int t0 = blockIdx.x * 128;
  const int b = t0 >> 12;
  const float* Wsrc = BETA ? W + (size_t)b * NH * D_TOK : W;

  for (int i = tid; i < NH * D_TOK / 4; i += 256) {
    const int r = (i * 4) >> 10, c = (i * 4) & 1023;
    const float4 v = reinterpret_cast<const float4*>(Wsrc)[i];
    ushort4 o;
    o.x = f32_to_bf16_rne(v.x);
    o.y = f32_to_bf16_rne(v.y);
    o.z = f32_to_bf16_rne(v.z);
    o.w = f32_to_bf16_rne(v.w);
    *reinterpret_cast<ushort4*>(&Wl[r][c]) = o;
  }

  const int srow = tid & 127;
  const u16* pX = X + (size_t)(t0 + srow) * D_TOK + (tid >> 7) * 8;
  const int d0 = wid * 512;
  const int d1 = 2048 + wid * 512;
  const int aOff = (kg * 128 + wid * 32 + lr) * 16;

#define STGL(SL, REG)                                             \
  do {                                                            \
    const int _o = (REG) * 32;                                    \
    GLD(pX + _o, &Xs[SL][d0]);                                    \
    GLD(pX + 16 + _o, &Xs[SL][d1]);                               \
  } while (0)

  STGL(0, 0);
  __syncthreads();

  f32x4 acc[2];
  acc[0] = (f32x4)0.f;
  acc[1] = (f32x4)0.f;

  for (int r = 0; r < 32; ++r) {
    const int sl = r & 1;
    if (r < 31) STGL(sl ^ 1, r + 1);
    bf16x8 af[2], bv;
#pragma unroll
    for (int j = 0; j < 2; ++j)
      af[j] = *reinterpret_cast<const bf16x8*>(
          (const char*)&Xs[sl][0] + aOff + j * 256);
    bv = *reinterpret_cast<const bf16x8*>(
        (const char*)&Wl[lr][0] + r * 64 + kg * 16);
#pragma unroll
    for (int j = 0; j < 2; ++j)
      acc[j] = __builtin_amdgcn_mfma_f32_16x16x32_bf16(af[j], bv, acc[j], 0, 0, 0);
    __syncthreads();
  }

#undef STGL

  const float bv_ = bias[lr] + (BETA ? cbeta[b * NH + lr] : 0.f);
#pragma unroll
  for (int j = 0; j < 2; ++j) {
#pragma unroll
    for (int reg = 0; reg < 4; ++reg) {
      const int t = t0 + wid * 32 + j * 16 + kg * 4 + reg;
      alpha[(size_t)t * NH + lr] = (acc[j][reg] + bv_) * INV_SQRT_DH;
    }
  }
}

// ---------------------------------------------------------------------------
// fused: fp32->bf16 for x_q / x_kv / q_w (blocks 0..2047), v_w transpose
// (blocks 2048..2303), zero-fill of zmem (blocks 2304..2335).
// ---------------------------------------------------------------------------
__global__ __launch_bounds__(256) void cvt_all(
    const float* __restrict__ a, const float* __restrict__ bsrc,
    const float* __restrict__ qw, const float* __restrict__ v_w,
    u16* __restrict__ oa, u16* __restrict__ ob, u16* __restrict__ oqw,
    u16* __restrict__ vwT, float4* __restrict__ zmem, int zcount4) {
  __shared__ float tile[64][65];
  if (blockIdx.x < 2048) {
    const int half = M_TOT * D_TOK / 4;
    const int wq4 = D_TOK * D_TOK / 4;
    int i = blockIdx.x * 256 + threadIdx.x;
    const int stride = 2048 * 256;
    for (; i < 2 * half + wq4; i += stride) {
      const float* src;
      u16* dst;
      int j;
      if (i < half) { src = a; dst = oa; j = i; }
      else if (i < 2 * half) { src = bsrc; dst = ob; j = i - half; }
      else { src = qw; dst = oqw; j = i - 2 * half; }
      const float4 v = reinterpret_cast<const float4*>(src)[j];
      ushort4 o;
      o.x = f32_to_bf16_rne(v.x);
      o.y = f32_to_bf16_rne(v.y);
      o.z = f32_to_bf16_rne(v.z);
      o.w = f32_to_bf16_rne(v.w);
      reinterpret_cast<ushort4*>(dst)[j] = o;
    }
  } else if (blockIdx.x < 2304) {
    const int tb = blockIdx.x - 2048;
    const int r0 = (tb >> 4) * 64;
    const int c0 = (tb & 15) * 64;
    for (int i = threadIdx.x; i < 4096; i += 256) {
      const int r = i >> 6, c = i & 63;
      tile[r][c] = v_w[(size_t)(r0 + r) * D_TOK + c0 + c];
    }
    __syncthreads();
    for (int i = threadIdx.x; i < 4096; i += 256) {
      const int rr = i >> 6, cc = i & 63;
      vwT[(size_t)(c0 + rr) * D_TOK + r0 + cc] = f32_to_bf16_rne(tile[cc][rr]);
    }
  } else {
    const float4 z = make_float4(0.f, 0.f, 0.f, 0.f);
    for (int i = (blockIdx.x - 2304) * 256 + threadIdx.x; i < zcount4;
         i += 32 * 256)
      zmem[i] = z;
  }
}

// ---------------------------------------------------------------------------
// scale_vbt: owsc = bf16(out_w*kglb) AND vbt[b][n] += wave-reduced dot.
// ---------------------------------------------------------------------------
__global__ __launch_bounds__(256) void scale_vbt(
    const float* __restrict__ ow, const float* __restrict__ kglb,
    const float* __restrict__ v_b, u16* __restrict__ owsc,
    float* __restrict__ vbt) {
  const int per_b = D_TOK * D_TOK / 4;
  int i = blockIdx.x * 256 + threadIdx.x;
  const int stride = gridDim.x * 256;
  const int lane = threadIdx.x & 63;
  for (; i < BATCH * per_b; i += stride) {
    const int b = i >> 18, j = i & (per_b - 1);
    const int k4 = j & 255, n = j >> 8;
    const float4 w = reinterpret_cast<const float4*>(ow)[j];
    const float4 s = reinterpret_cast<const float4*>(kglb)[b * 256 + k4];
    const float4 v = reinterpret_cast<const float4*>(v_b)[k4];
    const float wsx = w.x * s.x, wsy = w.y * s.y, wsz = w.z * s.z,
                wsw = w.w * s.w;
    ushort4 o;
    o.x = f32_to_bf16_rne(wsx);
    o.y = f32_to_bf16_rne(wsy);
    o.z = f32_to_bf16_rne(wsz);
    o.w = f32_to_bf16_rne(wsw);
    reinterpret_cast<ushort4*>(owsc)[i] = o;
    float p = wsx * v.x + wsy * v.y + wsz * v.z + wsw * v.w;
#pragma unroll
    for (int off = 32; off; off >>= 1) p += __shfl_xor(p, off, 64);
    if (lane == 0) atomicAdd(&vbt[(size_t)b * D_TOK + n], p);
  }
}

// ---------------------------------------------------------------------------
// mb2: Mb[b][h][n] += sum_{d in chunk} k_w[d][n]*qg[b][d]*wk[h][d]
// ---------------------------------------------------------------------------
__global__ __launch_bounds__(256) void mb2_kernel(
    const float* __restrict__ k_w, const float* __restrict__ wk,
    const float* __restrict__ qg, const float* __restrict__ k_b,
    float* __restrict__ Mb, float* __restrict__ cbeta) {
  __shared__ float wq[128 * 16];
  const int bidx = blockIdx.x;
  const int b = bidx >> 5;
  const int nc = (bidx >> 3) & 3;
  const int dc = bidx & 7;
  const int n = nc * 256 + threadIdx.x;
  const int d0 = dc * 128;
  const int tid = threadIdx.x;

  for (int e = tid; e < 128 * 16; e += 256) {
    const int d = e >> 4, h = e & 15;
    wq[e] = qg[(size_t)b * D_TOK + d0 + d] * wk[(size_t)h * D_TOK + d0 + d];
  }
  __syncthreads();

  float acc[NH];
#pragma unroll
  for (int h = 0; h < NH; h++) acc[h] = 0.f;
#pragma unroll 4
  for (int d = 0; d < 128; ++d) {
    const float kv = k_w[(size_t)(d0 + d) * D_TOK + n];
#pragma unroll
    for (int h = 0; h < NH; h++) acc[h] += kv * wq[d * 16 + h];
  }
#pragma unroll
  for (int h = 0; h < NH; h++)
    atomicAdd(&Mb[((size_t)b * NH + h) * D_TOK + n], acc[h]);

  if (nc == 0 && tid < 64) {
    const int h = tid & 15, dl = tid >> 4;
    float c = 0.f;
    for (int d = dl; d < 128; d += 4)
      c += k_b[d0 + d] * wq[d * 16 + h];
    c += __shfl_xor(c, 16, 64);
    c += __shfl_xor(c, 32, 64);
    if (dl == 0) atomicAdd(&cbeta[b * NH + h], c);
  }
}

// ---------------------------------------------------------------------------
// kglb2: kglb[b][d] = qg[b][d]*(sum_n xp[b][h(d)][n]*k_w[d][n] + k_b[d])
// ---------------------------------------------------------------------------
__global__ __launch_bounds__(256) void kglb2_kernel(
    const float* __restrict__ xp, const float* __restrict__ k_w,
    const float* __restrict__ qg, const float* __restrict__ k_b,
    float* __restrict__ kglb) {
  __shared__ float xs[D_TOK];
  const int b = blockIdx.x >> 6;
  const int d0 = (blockIdx.x & 63) * 16;
  const int h = d0 >> 6;
  const int tid = threadIdx.x, lane = tid & 63, wv = tid >> 6;

  reinterpret_cast<float4*>(xs)[tid] =
      reinterpret_cast<const float4*>(xp + ((size_t)b * NH + h) * D_TOK)[tid];
  __syncthreads();

#pragma unroll
  for (int i = 0; i < 4; ++i) {
    const int d = d0 + wv * 4 + i;
    const float4* kr = reinterpret_cast<const float4*>(k_w + (size_t)d * D_TOK);
    float s = 0.f;
#pragma unroll
    for (int k4 = 0; k4 < 4; ++k4) {
      const int j4 = lane + k4 * 64;
      const float4 kv = kr[j4];
      const float4 xv = reinterpret_cast<const float4*>(xs)[j4];
      s += kv.x * xv.x + kv.y * xv.y + kv.z * xv.z + kv.w * xv.w;
    }
#pragma unroll
    for (int off = 32; off; off >>= 1) s += __shfl_xor(s, off, 64);
    if (lane == 0)
      kglb[(size_t)b * D_TOK + d] = qg[(size_t)b * D_TOK + d] * (s + k_b[d]);
  }
}

// ---------------------------------------------------------------------------
// Per-(b,h): max + 1/sum(exp) over tokens.
// ---------------------------------------------------------------------------
__global__ __launch_bounds__(256) void softmax_prep(
    const float* __restrict__ al, float* __restrict__ smx,
    float* __restrict__ sinv) {
  __shared__ float red[4];
  const int b = blockIdx.x >> 4, h = blockIdx.x & 15;
  const int tid = threadIdx.x, lane = tid & 63, wid = tid >> 6;
  const float* col = al + (size_t)b * SEQ * NH + h;

  float mx = -INFINITY;
  for (int t = tid; t < SEQ; t += 256) mx = fmaxf(mx, col[(size_t)t * NH]);
#pragma unroll
  for (int off = 32; off; off >>= 1) mx = fmaxf(mx, __shfl_xor(mx, off, 64));
  if (lane == 0) red[wid] = mx;
  __syncthreads();
  mx = fmaxf(fmaxf(red[0], red[1]), fmaxf(red[2], red[3]));
  __syncthreads();

  float s = 0.f;
  for (int t = tid; t < SEQ; t += 256) s += __expf(col[(size_t)t * NH] - mx);
#pragma unroll
  for (int off = 32; off; off >>= 1) s += __shfl_xor(s, off, 64);
  if (lane == 0) red[wid] = s;
  __syncthreads();
  if (tid == 0) {
    const float tot = red[0] + red[1] + red[2] + red[3];
    smx[blockIdx.x] = mx;
    sinv[blockIdx.x] = 1.0f / tot;
  }
}

// ---------------------------------------------------------------------------
// qg pool: qg[b,d] += sum_t softmaxw[t,h(d)] * q_bf[b,t,d]  (atomics)
// ---------------------------------------------------------------------------
__global__ __launch_bounds__(256) void pool_accum_bf(
    const float* __restrict__ al, const u16* __restrict__ src,
    const float* __restrict__ smx, const float* __restrict__ sinv,
    float* __restrict__ g) {
  constexpr int TCH = 64;
  const int b = blockIdx.x / (SEQ / TCH);
  const int t0 = (blockIdx.x % (SEQ / TCH)) * TCH;
  const int d0 = threadIdx.x * 4;
  const int h = d0 >> 6;
  const float mx = smx[b * NH + h];
  const float inv = sinv[b * NH + h];

  float4 acc = make_float4(0.f, 0.f, 0.f, 0.f);
  const float* ap = al + ((size_t)b * SEQ + t0) * NH + h;
  const u16* sp = src + ((size_t)b * SEQ + t0) * D_TOK + d0;
#pragma unroll 2
  for (int t = 0; t < TCH; t++) {
    const float wgt = __expf(ap[(size_t)t * NH] - mx) * inv;
    const ushort4 v = *reinterpret_cast<const ushort4*>(sp + (size_t)t * D_TOK);
    acc.x += wgt * bf2f(v.x);
    acc.y += wgt * bf2f(v.y);
    acc.z += wgt * bf2f(v.z);
    acc.w += wgt * bf2f(v.w);
  }
  float* gp = g + (size_t)b * D_TOK + d0;
  atomicAdd(gp + 0, acc.x);
  atomicAdd(gp + 1, acc.y);
  atomicAdd(gp + 2, acc.z);
  atomicAdd(gp + 3, acc.w);
}

// ---------------------------------------------------------------------------
// xp pool: xp[b][h][n] += sum_t beta[t,h]*x_kv[t,n].  Grid 256.
// ---------------------------------------------------------------------------
__global__ __launch_bounds__(256) void xp_pool(
    const float* __restrict__ al, const u16* __restrict__ x,
    const float* __restrict__ smx, const float* __restrict__ sinv,
    float* __restrict__ xp) {
  constexpr int TCH = 128;
  __shared__ float wl[TCH][NH];
  const int b = blockIdx.x >> 5;
  const int t0 = (blockIdx.x & 31) * TCH;
  const int tid = threadIdx.x;
  for (int i = tid; i < TCH * NH; i += 256) {
    const int tt = i >> 4, h = i & 15;
    wl[tt][h] = __expf(al[((size_t)(b * SEQ + t0 + tt)) * NH + h] -
                       smx[b * NH + h]) *
                sinv[b * NH + h];
  }
  __syncthreads();

  const int n0 = tid * 4;
  float acc[NH][4];
#pragma unroll
  for (int h = 0; h < NH; h++)
#pragma unroll
    for (int c = 0; c < 4; c++) acc[h][c] = 0.f;
  const u16* xpt = x + ((size_t)b * SEQ + t0) * D_TOK + n0;
  for (int tt = 0; tt < TCH; tt++) {
    const ushort4 v = *reinterpret_cast<const ushort4*>(xpt + (size_t)tt * D_TOK);
    const float x0 = bf2f(v.x), x1 = bf2f(v.y), x2 = bf2f(v.z), x3 = bf2f(v.w);
#pragma unroll
    for (int h = 0; h < NH; h++) {
      const float w = wl[tt][h];
      acc[h][0] += w * x0;
      acc[h][1] += w * x1;
      acc[h][2] += w * x2;
      acc[h][3] += w * x3;
    }
  }
#pragma unroll
  for (int h = 0; h < NH; h++)
#pragma unroll
    for (int c = 0; c < 4; c++)
      atomicAdd(&xp[((size_t)b * NH + h) * D_TOK + n0 + c], acc[h][c]);
}

// ---------------------------------------------------------------------------
extern "C" void kernel_launch(void* const* d_in, const int* in_sizes, int n_in,
                              void* d_out, int out_size, void* d_ws,
                              size_t ws_size, hipStream_t stream) {
  const float* x_q   = (const float*)d_in[0];
  const float* x_kv  = (const float*)d_in[1];
  const float* q_w   = (const float*)d_in[2];
  const float* k_w   = (const float*)d_in[3];
  const float* v_w   = (const float*)d_in[4];
  const float* wq_w  = (const float*)d_in[5];
  const float* wk_w  = (const float*)d_in[6];
  const float* out_w = (const float*)d_in[7];
  const float* q_b   = (const float*)d_in[8];
  const float* k_b   = (const float*)d_in[9];
  const float* v_b   = (const float*)d_in[10];
  const float* wq_b  = (const float*)d_in[11];
  const float* wk_b  = (const float*)d_in[12];
  const float* out_b = (const float*)d_in[13];
  float* out = (float*)d_out;

  char* ws = (char*)d_ws;
  const size_t SZ_BF  = (size_t)M_TOT * D_TOK * sizeof(u16);
  const size_t SZ_WBF = (size_t)D_TOK * D_TOK * sizeof(u16);
  size_t off = 0;
  u16* xq_bf  = (u16*)(ws + off); off += SZ_BF;
  u16* xkv_bf = (u16*)(ws + off); off += SZ_BF;
  u16* q_bf   = (u16*)(ws + off); off += SZ_BF;
  u16* qw_bf  = (u16*)(ws + off); off += SZ_WBF;
  u16* vwT_bf = (u16*)(ws + off); off += SZ_WBF;
  u16* owsc   = (u16*)(ws + off); off += BATCH * SZ_WBF;
  u16* Nbt    = (u16*)(ws + off); off += BATCH * SZ_WBF;
  float* al   = (float*)(ws + off); off += (size_t)M_TOT * NH * 4;
  float* kglb = (float*)(ws + off); off += BATCH * D_TOK * 4;
  float* smx0 = (float*)(ws + off); off += BATCH * NH * 4;
  float* sinv0= (float*)(ws + off); off += BATCH * NH * 4;
  float* smx1 = (float*)(ws + off); off += BATCH * NH * 4;
  float* sinv1= (float*)(ws + off); off += BATCH * NH * 4;
  // ---- contiguous zero-init region (zeroed inside cvt_all) ----
  char* zstart = ws + off;
  float* xp   = (float*)(ws + off); off += (size_t)BATCH * NH * D_TOK * 4;
  float* Mb   = (float*)(ws + off); off += (size_t)BATCH * NH * D_TOK * 4;
  float* qg   = (float*)(ws + off); off += BATCH * D_TOK * 4;
  float* vbt  = (float*)(ws + off); off += BATCH * D_TOK * 4;
  float* zb   = (float*)(ws + off); off += D_TOK * 4;
  float* cbeta= (float*)(ws + off); off += BATCH * NH * 4;
  const int ZC4 = (int)((ws + off - zstart) / 16);  // float4 count

  // fused conversions + v_w transpose + zero-init
  cvt_all<<<2336, 256, 0, stream>>>(x_q, x_kv, q_w, v_w, xq_bf, xkv_bf,
                                    qw_bf, vwT_bf, (float4*)zstart, ZC4);

  // q = bf16(x_q @ q_w^T + q_b)  — proven 256^2 kernel (best measured)
  gemm_bf16<0, 4><<<512, 512, 0, stream>>>(xq_bf, qw_bf, q_b, nullptr,
                                           nullptr, q_bf, nullptr);
  // alpha (MFMA) -> softmax -> q_global
  logits_mfma<0><<<256, 256, 0, stream>>>(q_bf, wq_w, wq_b, nullptr, al);
  softmax_prep<<<BATCH * NH, 256, 0, stream>>>(al, smx0, sinv0);
  pool_accum_bf<<<BATCH * (SEQ / 64), 256, 0, stream>>>(al, q_bf, smx0, sinv0,
                                                        qg);
  // Mb + cbeta
  mb2_kernel<<<256, 256, 0, stream>>>(k_w, wk_w, qg, k_b, Mb, cbeta);
  // beta logits (MFMA, per-batch Mb)
  logits_mfma<1><<<256, 256, 0, stream>>>(xkv_bf, Mb, wk_b, cbeta, al);
  softmax_prep<<<BATCH * NH, 256, 0, stream>>>(al, smx1, sinv1);
  // per-head pools of x_kv
  xp_pool<<<256, 256, 0, stream>>>(al, xkv_bf, smx1, sinv1, xp);
  // k_global
  kglb2_kernel<<<512, 256, 0, stream>>>(xp, k_w, qg, k_b, kglb);
  // owsc = out_w * kglb AND vbt, fused
  scale_vbt<<<1024, 256, 0, stream>>>(out_w, kglb, v_b, owsc, vbt);
  // compose on gemm128 (512 blocks)
  gemm128_bf16<8><<<512, 256, 0, stream>>>(owsc, vwT_bf, zb, Nbt);
  // out = x_kv @ Nbt_b^T + out_b + vbt_b + q
  gemm_bf16<2, 4><<<512, 512, 0, stream>>>(xkv_bf, Nbt, out_b, vbt, out,
                                           nullptr, q_bf);
}